// Round 4
// baseline (149.854 us; speedup 1.0000x reference)
//
#include <hip/hip_runtime.h>
#include <math.h>

#define BATCH 64
#define KSL   32
#define DIM   256
#define NMASK 16384

// DPP move of a double (both 32-bit halves), compile-time ctrl.
// bound_ctrl=false + old=src: invalid source lanes keep own value (min-safe).
template<int CTRL>
__device__ __forceinline__ double dpp_mov_f64(double x) {
  union { double d; int i[2]; } a, r;
  a.d = x;
  r.i[0] = __builtin_amdgcn_update_dpp(a.i[0], a.i[0], CTRL, 0xF, 0xF, false);
  r.i[1] = __builtin_amdgcn_update_dpp(a.i[1], a.i[1], CTRL, 0xF, 0xF, false);
  return r.d;
}

__device__ __forceinline__ double readlane_f64(double x, int lane) {
  union { double d; unsigned long long u; } a; a.d = x;
  int lo = __builtin_amdgcn_readlane((int)(a.u & 0xFFFFFFFFull), lane);
  int hi = __builtin_amdgcn_readlane((int)(a.u >> 32), lane);
  union { unsigned long long u; double d; } r;
  r.u = ((unsigned long long)(unsigned)hi << 32) | (unsigned)lo;
  return r.d;
}

// Branchless select cc[idx] from a statically-indexed register array via a
// 5-level cndmask tree (idx is wave-uniform). No scratch, no LDS latency.
__device__ __forceinline__ float sel32(const float (&cc)[KSL], int idx) {
  float l0[16], l1[8], l2[4], l3[2];
  bool b4 = (idx & 16) != 0;
  #pragma unroll
  for (int r = 0; r < 16; ++r) l0[r] = b4 ? cc[r + 16] : cc[r];
  bool b3 = (idx & 8) != 0;
  #pragma unroll
  for (int r = 0; r < 8; ++r) l1[r] = b3 ? l0[r + 8] : l0[r];
  bool b2 = (idx & 4) != 0;
  #pragma unroll
  for (int r = 0; r < 4; ++r) l2[r] = b2 ? l1[r + 4] : l1[r];
  bool b1 = (idx & 2) != 0;
  #pragma unroll
  for (int r = 0; r < 2; ++r) l3[r] = b1 ? l2[r + 2] : l2[r];
  return (idx & 1) ? l3[1] : l3[0];
}

// ---------------------------------------------------------------------------
// One block per batch, 512 threads:
//   all    : cost matrix (LDS-staged, chunked)
//   wave 0 : reference-exact greedy assignment (fp64 duals, register-resident
//            cost column, software-pipelined cur0 = c - u0)
//   waves 1-7 (448 thr): batch-b mask column sums (2 MB, hidden under solver)
//   all    : matched L2^2 loss + util weighting -> bloss[b]
// ---------------------------------------------------------------------------
__global__ __launch_bounds__(512) void batch_kernel(
    const float* __restrict__ slots_t, const float* __restrict__ slots_t1,
    const float* __restrict__ masks, float* __restrict__ bloss) {
  int b = blockIdx.x, tid = threadIdx.x;
  __shared__ float as[KSL][64];
  __shared__ float bs[KSL][65];   // pad: conflict-free
  __shared__ float cs[KSL][KSL];
  __shared__ float red[448][4];
  __shared__ float util[KSL], ls[KSL];
  __shared__ int   sh_match[KSL];

  const float* ab = slots_t  + (size_t)b * KSL * DIM;
  const float* bb = slots_t1 + (size_t)b * KSL * DIM;

  // ---- cost[i][j] = ||a_i - b_j|| (fp32) ----
  float acc[2] = {0.f, 0.f};
  for (int c = 0; c < DIM / 64; ++c) {
    __syncthreads();
    for (int e = tid; e < KSL * 64; e += 512) {
      int kk = e >> 6, dd = e & 63;
      as[kk][dd] = ab[kk * DIM + c * 64 + dd];
      bs[kk][dd] = bb[kk * DIM + c * 64 + dd];
    }
    __syncthreads();
    #pragma unroll
    for (int p4 = 0; p4 < 2; ++p4) {
      int id = p4 * 512 + tid;
      int i = id >> 5, j = id & 31;
      float s = acc[p4];
      #pragma unroll
      for (int dd = 0; dd < 64; ++dd) {
        float df = as[i][dd] - bs[j][dd];
        s = fmaf(df, df, s);
      }
      acc[p4] = s;
    }
  }
  __syncthreads();
  #pragma unroll
  for (int p4 = 0; p4 < 2; ++p4) {
    int id = p4 * 512 + tid;
    cs[id >> 5][id & 31] = sqrtf(acc[p4]);
  }
  __syncthreads();

  if (tid < 64) {
    if (tid < KSL) {
      // ---- greedy assignment, reference-exact (fp64) ----
      const int col = tid;
      float cc[KSL];
      #pragma unroll
      for (int r = 0; r < KSL; ++r) cc[r] = cs[r][col];  // column in VGPRs
      const double INF = __builtin_inf();
      double v = 0.0, up = 0.0;
      int pcol = 0;
      for (int i = 1; i <= KSL; ++i) {
        double u_i = 0.0;
        int used = 0;
        double cur0 = (double)sel32(cc, i - 1);   // c - u[i], u[i]=0
        for (;;) {
          double cur = cur0 - v;                  // fl(fl(c-u0)-v): ref order
          double masked = used ? INF : cur;
          double m = masked;
          m = fmin(m, dpp_mov_f64<0xB1>(m));      // quad_perm [1,0,3,2]
          m = fmin(m, dpp_mov_f64<0x4E>(m));      // quad_perm [2,3,0,1]
          m = fmin(m, dpp_mov_f64<0x141>(m));     // row_half_mirror
          m = fmin(m, dpp_mov_f64<0x140>(m));     // row_mirror
          m = fmin(m, dpp_mov_f64<0x142>(m));     // row_bcast15 -> lane31=min
          double delta = readlane_f64(m, 31);
          unsigned eq = (unsigned)__ballot(masked == delta);
          int j1c = __builtin_amdgcn_readfirstlane(__ffs(eq) - 1);
          int i0n = __builtin_amdgcn_readlane(pcol, j1c);   // p[j1]
          double u0n = readlane_f64(up, j1c);               // u[p[j1]] pre-upd
          int rown = (i0n > 0) ? (i0n - 1) : 0;
          double cur0n = (double)sel32(cc, rown) - u0n;     // next iter's c-u0
          if (used) { up += delta; v -= delta; }
          u_i += delta;
          if (i0n == 0) {                       // free column: p[j1]=i, done
            if (col == j1c) { pcol = i; up = u_i; }
            break;
          }
          if (col == j1c) used = 1;             // used[j1] = True
          cur0 = cur0n;
        }
      }
      sh_match[pcol - 1] = col;                 // ans[p[j]-1] = j-1
    }
    // lanes 32-63 of wave 0: idle (masked), reconverge below
  } else {
    // ---- batch-b mask sums: masks[b][n][k], 2 MB coalesced float4 ----
    int idx = tid - 64;            // 0..447
    int q = idx & 7;               // float4 slot within 32-float row
    int r = idx >> 3;              // 0..55
    const float4* m4 = (const float4*)(masks + (size_t)b * NMASK * KSL);
    float4 a4 = make_float4(0.f, 0.f, 0.f, 0.f);
    #pragma unroll 4
    for (int rr = r; rr < NMASK; rr += 56) {
      float4 t = m4[rr * 8 + q];
      a4.x += t.x; a4.y += t.y; a4.z += t.z; a4.w += t.w;
    }
    red[idx][0] = a4.x; red[idx][1] = a4.y;
    red[idx][2] = a4.z; red[idx][3] = a4.w;
  }
  __syncthreads();

  // ---- util reduce + matched L2^2 loss ----
  if (tid < KSL) {
    int q = tid >> 2, c = tid & 3;
    float s = 0.f;
    for (int g = 0; g < 56; ++g) s += red[g * 8 + q][c];
    util[tid] = s;
  }
  {
    int k = tid >> 4, l16 = tid & 15;
    int mk = sh_match[k];
    const float4* x4 = (const float4*)(ab + k * DIM);
    const float4* y4 = (const float4*)(bb + mk * DIM);
    float s = 0.f;
    #pragma unroll
    for (int d = 0; d < 4; ++d) {
      float4 xv = x4[l16 + d * 16];
      float4 yv = y4[l16 + d * 16];
      float dx = xv.x - yv.x, dy = xv.y - yv.y;
      float dz = xv.z - yv.z, dw = xv.w - yv.w;
      s = fmaf(dx, dx, s); s = fmaf(dy, dy, s);
      s = fmaf(dz, dz, s); s = fmaf(dw, dw, s);
    }
    #pragma unroll
    for (int off = 8; off > 0; off >>= 1) s += __shfl_down(s, off, 16);
    if (l16 == 0) ls[k] = s;
  }
  __syncthreads();
  if (tid == 0) {
    float us = 0.f;
    for (int kk = 0; kk < KSL; ++kk) us += util[kk];
    float s = 0.f;
    for (int kk = 0; kk < KSL; ++kk) s += ls[kk] * (util[kk] / us);
    bloss[b] = s;
  }
}

__global__ void reduce_kernel(const float* __restrict__ bloss,
                              float* __restrict__ out) {
  float v = bloss[threadIdx.x];
  #pragma unroll
  for (int off = 32; off > 0; off >>= 1) v += __shfl_down(v, off);
  if (threadIdx.x == 0) out[0] = v / (float)(BATCH * KSL);
}

extern "C" void kernel_launch(void* const* d_in, const int* in_sizes, int n_in,
                              void* d_out, int out_size, void* d_ws, size_t ws_size,
                              hipStream_t stream) {
  const float* slots_t  = (const float*)d_in[0];
  const float* slots_t1 = (const float*)d_in[1];
  const float* masks    = (const float*)d_in[2];

  float* bloss = (float*)d_ws;   // 64 floats

  batch_kernel<<<BATCH, 512, 0, stream>>>(slots_t, slots_t1, masks, bloss);
  reduce_kernel<<<1, 64, 0, stream>>>(bloss, (float*)d_out);
}